// Round 5
// baseline (225.128 us; speedup 1.0000x reference)
//
#include <hip/hip_runtime.h>
#include <stdint.h>

typedef __bf16 bf16x8 __attribute__((ext_vector_type(8)));
typedef float f32x4 __attribute__((ext_vector_type(4)));

#define B_ 16
#define C_ 512
#define S_ 1024   // W*H = 32*32
#define N1 1536   // 3C

// ---------- bf16 helpers (manual RNE) ----------
__device__ inline unsigned short f2b(float f) {
    unsigned int u = __builtin_bit_cast(unsigned int, f);
    unsigned int lsb = (u >> 16) & 1u;
    u += 0x7fffu + lsb;
    return (unsigned short)(u >> 16);
}
__device__ inline float b2f(unsigned int s) {
    unsigned int u = (s & 0xffffu) << 16;
    return __builtin_bit_cast(float, u);
}

// async global->LDS, 16B per lane. LDS dest must be wave-uniform base + lane*16.
__device__ inline void gl_lds16(const unsigned short* g, unsigned short* l) {
    __builtin_amdgcn_global_load_lds(
        (const __attribute__((address_space(1))) void*)(g),
        (__attribute__((address_space(3))) void*)(l),
        16, 0, 0);
}

// ---------- prep: x (B,C,S) f32 -> xT (B,S,C) bf16 ----------
__global__ void transpose_convert_x(const float* __restrict__ x, unsigned short* __restrict__ xT) {
    __shared__ float tile[32][33];
    int b = blockIdx.z;
    int c0 = blockIdx.y * 32;
    int s0 = blockIdx.x * 32;
    int tx = threadIdx.x, ty = threadIdx.y; // (32,8)
    const float* xp = x + ((size_t)b * C_ + c0) * S_ + s0;
#pragma unroll
    for (int i = 0; i < 4; i++)
        tile[ty + i * 8][tx] = xp[(size_t)(ty + i * 8) * S_ + tx];
    __syncthreads();
    unsigned short* op = xT + ((size_t)b * S_ + s0) * C_ + c0;
#pragma unroll
    for (int i = 0; i < 4; i++)
        op[(size_t)(ty + i * 8) * C_ + tx] = f2b(tile[tx][ty + i * 8]);
}

// ---------- prep: convert w1,w2 to bf16 + zero the 5 sum planes ----------
// work items are float4-granular: w1 = 196608, w2 = 65536, sums = 30720
__global__ __launch_bounds__(256) void misc_prep(
    const float* __restrict__ w1, const float* __restrict__ w2,
    unsigned short* __restrict__ w1b, unsigned short* __restrict__ w2b,
    float* __restrict__ sums)
{
    int i = blockIdx.x * 256 + threadIdx.x;
    if (i < 196608) {
        float4 v = ((const float4*)w1)[i];
        ((ushort4*)w1b)[i] = make_ushort4(f2b(v.x), f2b(v.y), f2b(v.z), f2b(v.w));
    } else if (i < 262144) {
        int j = i - 196608;
        float4 v = ((const float4*)w2)[j];
        ((ushort4*)w2b)[j] = make_ushort4(f2b(v.x), f2b(v.y), f2b(v.z), f2b(v.w));
    } else if (i < 292864) {
        int j = i - 262144;
        ((float4*)sums)[j] = make_float4(0.f, 0.f, 0.f, 0.f);
    }
}

// ---------- GEMM: C[m,n] = A[m,:] . Wt[n,:] + bias[n], K=512 ----------
// 256x128 block tile, 4 waves stacked in M (wave = 64 rows x 128 cols, acc 4x8).
// global_load_lds width-16 staging, unpadded 64B LDS rows.
// DO_SUMS: accumulate T/H0/H31/C0/C31 planes (16x1536 each) for the gating a-sum.
// TRANS_OUT: store f32 out[(b*512+n)*1024 + s], m = b*1024+s (N=512).
template <bool TRANS_OUT, bool DO_SUMS>
__global__ __launch_bounds__(256) void gemm_bf16(
    const unsigned short* __restrict__ A,
    const unsigned short* __restrict__ Wt,
    const float* __restrict__ bias,
    void* __restrict__ Cout, int N,
    float* __restrict__ Tsum, float* __restrict__ H0, float* __restrict__ H31,
    float* __restrict__ C0, float* __restrict__ C31)
{
    const int K = 512;
    __shared__ __align__(16) unsigned short As[256 * 32]; // 16 KB, 64B rows
    __shared__ __align__(16) unsigned short Bs[128 * 32]; //  8 KB
    int m0 = blockIdx.x * 256;
    int n0 = blockIdx.y * 128;
    int tid = threadIdx.x;
    int lane = tid & 63, wid = tid >> 6;
    int wm = wid * 64;
    int quad = lane >> 4, l16 = lane & 15;
    int chA = wid * 64 + lane;   // lane-consecutive chunk id within each 256-group
    const unsigned short* Ab = A + (size_t)m0 * K;
    const unsigned short* Bb = Wt + (size_t)n0 * K;

    f32x4 acc[4][8] = {};

    for (int kt = 0; kt < K; kt += 32) {
        __syncthreads();
#pragma unroll
        for (int i = 0; i < 4; i++) {        // A: 1024 chunks of 16B
            int ch = chA + i * 256;
            int m = ch >> 2, kc = ch & 3;
            gl_lds16(Ab + (size_t)m * K + kt + kc * 8, &As[ch * 8]);
        }
#pragma unroll
        for (int i = 0; i < 2; i++) {        // B: 512 chunks of 16B
            int ch = chA + i * 256;
            int m = ch >> 2, kc = ch & 3;
            gl_lds16(Bb + (size_t)m * K + kt + kc * 8, &Bs[ch * 8]);
        }
        __syncthreads();
        bf16x8 af[4], bfr[8];
#pragma unroll
        for (int t = 0; t < 4; t++)
            af[t] = *(const bf16x8*)&As[(wm + t * 16 + l16) * 32 + quad * 8];
#pragma unroll
        for (int t = 0; t < 8; t++)
            bfr[t] = *(const bf16x8*)&Bs[(t * 16 + l16) * 32 + quad * 8];
#pragma unroll
        for (int mt = 0; mt < 4; mt++)
#pragma unroll
            for (int nt = 0; nt < 8; nt++)
                acc[mt][nt] = __builtin_amdgcn_mfma_f32_16x16x32_bf16(af[mt], bfr[nt], acc[mt][nt], 0, 0, 0);
    }

    // ---- write output ----
#pragma unroll
    for (int mt = 0; mt < 4; mt++) {
#pragma unroll
        for (int nt = 0; nt < 8; nt++) {
            int n = n0 + nt * 16 + l16;
            float bv = bias[n];
            int mbase = m0 + wm + mt * 16 + quad * 4;
            if (!TRANS_OUT) {
                unsigned short* Y = (unsigned short*)Cout;
#pragma unroll
                for (int r = 0; r < 4; r++)
                    Y[(size_t)(mbase + r) * N + n] = f2b(acc[mt][nt][r] + bv);
            } else {
                float* Z = (float*)Cout;
                int b = mbase >> 10;
                int s = mbase & 1023;
                float4 v = make_float4(acc[mt][nt][0] + bv, acc[mt][nt][1] + bv,
                                       acc[mt][nt][2] + bv, acc[mt][nt][3] + bv);
                *(float4*)(&Z[((size_t)(b * 512 + n)) * 1024 + s]) = v;
            }
        }
    }

    // ---- fused a-sum accumulators ----
    // m_local(wave) = mt*16 + quad*4 + r in [0,64); h = (wm+m_local)&31; w = wlo + ((wm+m_local)>>5)
    if (DO_SUMS) {
        int b = m0 >> 10;
        int wlo = (m0 & 1023) >> 5; // first of 8 w-rows in this block
#pragma unroll
        for (int nt = 0; nt < 8; nt++) {
            int n = n0 + nt * 16 + l16;
            float bv = bias[n];
            // total over this wave's 64 m's
            float tT = 0.f;
#pragma unroll
            for (int mt = 0; mt < 4; mt++)
#pragma unroll
                for (int r = 0; r < 4; r++) tT += acc[mt][nt][r] + bv;
            tT += __shfl_xor(tT, 16);
            tT += __shfl_xor(tT, 32);
            if (quad == 0) {
                atomicAdd(&Tsum[b * 1536 + n], tT);
                // h==0 rows of this wave: m_local = 0,32 -> (mt 0,2, quad0, r0)
                float th0 = acc[0][nt][0] + acc[2][nt][0] + 2.f * bv;
                atomicAdd(&H0[b * 1536 + n], th0);
            }
            if (quad == 3) {
                // h==31 rows: m_local = 31,63 -> (mt 1,3, quad3, r3)
                float th31 = acc[1][nt][3] + acc[3][nt][3] + 2.f * bv;
                atomicAdd(&H31[b * 1536 + n], th31);
            }
            if (wlo == 0 && wm == 0) { // w==0 slice: global m < 32 -> wid0, mt 0,1
                float tc = 0.f;
#pragma unroll
                for (int mt = 0; mt < 2; mt++)
#pragma unroll
                    for (int r = 0; r < 4; r++) tc += acc[mt][nt][r] + bv;
                tc += __shfl_xor(tc, 16);
                tc += __shfl_xor(tc, 32);
                if (quad == 0) atomicAdd(&C0[b * 1536 + n], tc);
            }
            if (wlo == 24 && wm == 192) { // w==31 slice: global m in [992,1024) -> wid3, mt 2,3
                float tc = 0.f;
#pragma unroll
                for (int mt = 2; mt < 4; mt++)
#pragma unroll
                    for (int r = 0; r < 4; r++) tc += acc[mt][nt][r] + bv;
                tc += __shfl_xor(tc, 16);
                tc += __shfl_xor(tc, 32);
                if (quad == 0) atomicAdd(&C31[b * 1536 + n], tc);
            }
        }
    }
}

// ---------- layer1: reconstruct a[b,:] from sum planes, then wave-dot ----------
// a[b,c]: q=c>>7, sgn=(q&1)?-1:+1,
//   e = (q<2) ? (C0-C31)[n1]+(H0-H31)[n2] : (H0-H31)[n1]+(C0-C31)[n2]
//   a = T[n1]+T[n2]+T[n3] + sgn*e       (n1=c, n2=512+c, n3=1024+c)
__global__ __launch_bounds__(256) void mlp_layer1(
    const float* __restrict__ sums, const float* __restrict__ wa,
    const float* __restrict__ ba, float* __restrict__ h)
{
    __shared__ float sa[512];
    int b = blockIdx.x >> 7;
    int t = threadIdx.x;
    const float* Tp   = sums;
    const float* H0p  = sums + 24576;
    const float* H31p = sums + 49152;
    const float* C0p  = sums + 73728;
    const float* C31p = sums + 98304;
#pragma unroll
    for (int j = 0; j < 2; j++) {
        int c = t + j * 256;
        int q = c >> 7;
        int n1 = b * 1536 + c;
        float t123 = Tp[n1] + Tp[n1 + 512] + Tp[n1 + 1024];
        float sC1 = C0p[n1] - C31p[n1];
        float sH1 = H0p[n1] - H31p[n1];
        float sC2 = C0p[n1 + 512] - C31p[n1 + 512];
        float sH2 = H0p[n1 + 512] - H31p[n1 + 512];
        float e = (q < 2) ? (sC1 + sH2) : (sH1 + sC2);
        sa[c] = t123 + ((q & 1) ? -e : e);
    }
    __syncthreads();
    int lane = t & 63, wid = t >> 6;
    int o = (blockIdx.x & 127) * 4 + wid;
    const float4* wr = (const float4*)(wa + (size_t)o * 512);
    float4 w0 = wr[lane * 2], w1v = wr[lane * 2 + 1];
    float4 a0 = ((const float4*)sa)[lane * 2], a1 = ((const float4*)sa)[lane * 2 + 1];
    float dot = w0.x * a0.x + w0.y * a0.y + w0.z * a0.z + w0.w * a0.w
              + w1v.x * a1.x + w1v.y * a1.y + w1v.z * a1.z + w1v.w * a1.w;
#pragma unroll
    for (int off = 32; off; off >>= 1) dot += __shfl_down(dot, off);
    if (lane == 0) {
        float v = dot + ba[o];
        h[b * 512 + o] = 0.5f * v * (1.0f + erff(v * 0.7071067811865475f));
    }
}

// ---------- layer2: hat[b*1536+o] = dot(h[b,:], wb[o,:]) + bb[o] ----------
__global__ __launch_bounds__(256) void mlp_layer2(
    const float* __restrict__ h, const float* __restrict__ wb,
    const float* __restrict__ bb, float* __restrict__ hat)
{
    int gw = (blockIdx.x * 256 + threadIdx.x) >> 6; // 24576 waves
    int lane = threadIdx.x & 63;
    int b = gw / 1536;
    int o = gw - b * 1536;
    const float4* wr = (const float4*)(wb + (size_t)o * 512);
    const float4* hr = (const float4*)(h + (size_t)b * 512);
    float4 w0 = wr[lane * 2], w1 = wr[lane * 2 + 1];
    float4 h0 = hr[lane * 2], h1 = hr[lane * 2 + 1];
    float dot = w0.x * h0.x + w0.y * h0.y + w0.z * h0.z + w0.w * h0.w
              + w1.x * h1.x + w1.y * h1.y + w1.z * h1.z + w1.w * h1.w;
#pragma unroll
    for (int off = 32; off; off >>= 1) dot += __shfl_down(dot, off);
    if (lane == 0)
        hat[(size_t)b * 1536 + o] = dot + bb[o];
}

// ---------- combine (softmax inline): out[b,s,c] = sum_j g_j * x_j (bf16) ----------
__global__ __launch_bounds__(256) void combine_softmax(
    const unsigned short* __restrict__ y, const float* __restrict__ hat,
    unsigned short* __restrict__ outT)
{
    int b = blockIdx.y;
    int t = threadIdx.x;
    int w = blockIdx.x * 4 + (t >> 6);
    int c8 = (t & 63) * 8;
    int q = c8 >> 7;
    int dw1 = (q == 0) ? -1 : (q == 1) ? 1 : 0;
    int dh1 = (q == 2) ? -1 : (q == 3) ? 1 : 0;
    int dh2 = (q == 0) ? -1 : (q == 1) ? 1 : 0;
    int dw2 = (q == 2) ? -1 : (q == 3) ? 1 : 0;
    float g0[8], g1[8], g2[8];
#pragma unroll
    for (int j = 0; j < 8; j++) {
        int c = c8 + j;
        float h0 = hat[b * 1536 + c];
        float h1 = hat[b * 1536 + 512 + c];
        float h2 = hat[b * 1536 + 1024 + c];
        float mx = fmaxf(h0, fmaxf(h1, h2));
        float e0 = __expf(h0 - mx), e1 = __expf(h1 - mx), e2 = __expf(h2 - mx);
        float inv = 1.0f / (e0 + e1 + e2);
        g0[j] = e0 * inv; g1[j] = e1 * inv; g2[j] = e2 * inv;
    }
    int w1i = min(max(w + dw1, 0), 31);
    int w2i = min(max(w + dw2, 0), 31);
    size_t base = (size_t)b * S_;
    for (int h = 0; h < 32; h++) {
        int h1i = min(max(h + dh1, 0), 31);
        int h2i = min(max(h + dh2, 0), 31);
        uint4 u1 = *(const uint4*)&y[(base + w1i * 32 + h1i) * N1 + c8];
        uint4 u2 = *(const uint4*)&y[(base + w2i * 32 + h2i) * N1 + 512 + c8];
        uint4 u3 = *(const uint4*)&y[(base + w * 32 + h) * N1 + 1024 + c8];
        unsigned int p[4];
        const unsigned int* a1 = &u1.x;
        const unsigned int* a2 = &u2.x;
        const unsigned int* a3 = &u3.x;
#pragma unroll
        for (int k = 0; k < 4; k++) {
            int j = k * 2;
            float lo = g0[j] * b2f(a1[k]) + g1[j] * b2f(a2[k]) + g2[j] * b2f(a3[k]);
            float hi = g0[j + 1] * b2f(a1[k] >> 16) + g1[j + 1] * b2f(a2[k] >> 16) + g2[j + 1] * b2f(a3[k] >> 16);
            p[k] = (unsigned int)f2b(lo) | ((unsigned int)f2b(hi) << 16);
        }
        *(uint4*)&outT[(base + w * 32 + h) * 512 + c8] = make_uint4(p[0], p[1], p[2], p[3]);
    }
}

extern "C" void kernel_launch(void* const* d_in, const int* in_sizes, int n_in,
                              void* d_out, int out_size, void* d_ws, size_t ws_size,
                              hipStream_t stream) {
    const float* x  = (const float*)d_in[0];
    const float* w1 = (const float*)d_in[1];
    const float* b1 = (const float*)d_in[2];
    const float* wa = (const float*)d_in[3];
    const float* ba = (const float*)d_in[4];
    const float* wb = (const float*)d_in[5];
    const float* bb = (const float*)d_in[6];
    const float* w2 = (const float*)d_in[7];
    const float* b2 = (const float*)d_in[8];
    float* out = (float*)d_out;

    char* ws = (char*)d_ws;
    unsigned short* xT   = (unsigned short*)(ws);              // 16 MB (dead after gemm1)
    unsigned short* outT = (unsigned short*)(ws);              // aliases xT (combine runs after gemm1)
    unsigned short* w1b  = (unsigned short*)(ws + 16777216);   // 1.5 MB
    unsigned short* w2b  = (unsigned short*)(ws + 18350080);   // 0.5 MB
    unsigned short* y    = (unsigned short*)(ws + 18874368);   // 48 MB: (B,S,3C) bf16
    float* sums          = (float*)(ws + 69206016);            // 5 x 96 KB: T,H0,H31,C0,C31
    float* h_buf         = (float*)(ws + 69697536);            // 32 KB
    float* hat_buf       = (float*)(ws + 69730304);            // 96 KB

    float* Tsum = sums;
    float* H0   = sums + 24576;
    float* H31  = sums + 49152;
    float* C0   = sums + 73728;
    float* C31  = sums + 98304;

    transpose_convert_x<<<dim3(32, 16, 16), dim3(32, 8), 0, stream>>>(x, xT);
    misc_prep<<<dim3(1144), dim3(256), 0, stream>>>(w1, w2, w1b, w2b, sums);
    gemm_bf16<false, true><<<dim3(64, 12), dim3(256), 0, stream>>>(
        xT, w1b, b1, (void*)y, 1536, Tsum, H0, H31, C0, C31);
    mlp_layer1<<<dim3(2048), dim3(256), 0, stream>>>(sums, wa, ba, h_buf);
    mlp_layer2<<<dim3(6144), dim3(256), 0, stream>>>(h_buf, wb, bb, hat_buf);
    combine_softmax<<<dim3(8, 16), dim3(256), 0, stream>>>(y, hat_buf, outT);
    gemm_bf16<true, false><<<dim3(64, 4), dim3(256), 0, stream>>>(
        outT, w2b, b2, (void*)out, 512, nullptr, nullptr, nullptr, nullptr, nullptr);
}

// Round 6
// 196.211 us; speedup vs baseline: 1.1474x; 1.1474x over previous
//
#include <hip/hip_runtime.h>
#include <stdint.h>

typedef __bf16 bf16x8 __attribute__((ext_vector_type(8)));
typedef float f32x4 __attribute__((ext_vector_type(4)));

#define B_ 16
#define C_ 512
#define S_ 1024   // W*H = 32*32
#define N1 1536   // 3C

// ---------- bf16 helpers (manual RNE) ----------
__device__ inline unsigned short f2b(float f) {
    unsigned int u = __builtin_bit_cast(unsigned int, f);
    unsigned int lsb = (u >> 16) & 1u;
    u += 0x7fffu + lsb;
    return (unsigned short)(u >> 16);
}
__device__ inline float b2f(unsigned int s) {
    unsigned int u = (s & 0xffffu) << 16;
    return __builtin_bit_cast(float, u);
}

// async global->LDS, 16B per lane. LDS dest must be wave-uniform base + lane*16.
__device__ inline void gl_lds16(const unsigned short* g, unsigned short* l) {
    __builtin_amdgcn_global_load_lds(
        (const __attribute__((address_space(1))) void*)(g),
        (__attribute__((address_space(3))) void*)(l),
        16, 0, 0);
}

// ---------- prep: x (B,C,S) f32 -> xT (B,S,C) bf16 ----------
__global__ void transpose_convert_x(const float* __restrict__ x, unsigned short* __restrict__ xT) {
    __shared__ float tile[32][33];
    int b = blockIdx.z;
    int c0 = blockIdx.y * 32;
    int s0 = blockIdx.x * 32;
    int tx = threadIdx.x, ty = threadIdx.y; // (32,8)
    const float* xp = x + ((size_t)b * C_ + c0) * S_ + s0;
#pragma unroll
    for (int i = 0; i < 4; i++)
        tile[ty + i * 8][tx] = xp[(size_t)(ty + i * 8) * S_ + tx];
    __syncthreads();
    unsigned short* op = xT + ((size_t)b * S_ + s0) * C_ + c0;
#pragma unroll
    for (int i = 0; i < 4; i++)
        op[(size_t)(ty + i * 8) * C_ + tx] = f2b(tile[tx][ty + i * 8]);
}

// ---------- prep: convert w1,w2 to bf16 + zero the 5 sum planes ----------
// work items are float4-granular: w1 = 196608, w2 = 65536, sums = 30720
__global__ __launch_bounds__(256) void misc_prep(
    const float* __restrict__ w1, const float* __restrict__ w2,
    unsigned short* __restrict__ w1b, unsigned short* __restrict__ w2b,
    float* __restrict__ sums)
{
    int i = blockIdx.x * 256 + threadIdx.x;
    if (i < 196608) {
        float4 v = ((const float4*)w1)[i];
        ((ushort4*)w1b)[i] = make_ushort4(f2b(v.x), f2b(v.y), f2b(v.z), f2b(v.w));
    } else if (i < 262144) {
        int j = i - 196608;
        float4 v = ((const float4*)w2)[j];
        ((ushort4*)w2b)[j] = make_ushort4(f2b(v.x), f2b(v.y), f2b(v.z), f2b(v.w));
    } else if (i < 292864) {
        int j = i - 262144;
        ((float4*)sums)[j] = make_float4(0.f, 0.f, 0.f, 0.f);
    }
}

// ---------- GEMM: C[m,n] = A[m,:] . Wt[n,:] + bias[n], K=512 ----------
// 128x128 tile (R4-proven), explicit LDS double-buffer: stage tile k+1 while
// computing tile k; ONE __syncthreads per K-step.
// DO_SUMS: accumulate T/H0/H31/C0/C31 planes (16x1536 each) for the gating a-sum.
// TRANS_OUT: store f32 out[(b*512+n)*1024 + s], m = b*1024+s (N=512).
template <bool TRANS_OUT, bool DO_SUMS>
__global__ __launch_bounds__(256) void gemm_bf16(
    const unsigned short* __restrict__ A,
    const unsigned short* __restrict__ Wt,
    const float* __restrict__ bias,
    void* __restrict__ Cout, int N,
    float* __restrict__ Tsum, float* __restrict__ H0, float* __restrict__ H31,
    float* __restrict__ C0, float* __restrict__ C31)
{
    const int K = 512;
    __shared__ __align__(16) unsigned short As[2][128 * 32]; // 2 x 8 KB, 64B rows
    __shared__ __align__(16) unsigned short Bs[2][128 * 32];
    int m0 = blockIdx.x * 128;
    int n0 = blockIdx.y * 128;
    int tid = threadIdx.x;
    int lane = tid & 63, wid = tid >> 6;
    int wm = (wid >> 1) * 64, wn = (wid & 1) * 64;
    int quad = lane >> 4, l16 = lane & 15;
    int ch0 = wid * 128 + lane;
    const unsigned short* Ab = A + (size_t)m0 * K;
    const unsigned short* Bb = Wt + (size_t)n0 * K;

    f32x4 acc[4][4] = {};

    // prologue: stage tile 0 into buffer 0
#pragma unroll
    for (int i = 0; i < 2; i++) {
        int ch = ch0 + i * 64;
        int m = ch >> 2, kc = ch & 3;
        size_t go = (size_t)m * K + kc * 8;
        gl_lds16(Ab + go, &As[0][ch * 8]);
        gl_lds16(Bb + go, &Bs[0][ch * 8]);
    }

    int cur = 0;
    for (int kt = 0; kt < K; kt += 32) {
        __syncthreads();   // drains this buffer's staging loads (issued last iter)
        if (kt + 32 < K) {
            int nxt = cur ^ 1;
#pragma unroll
            for (int i = 0; i < 2; i++) {
                int ch = ch0 + i * 64;
                int m = ch >> 2, kc = ch & 3;
                size_t go = (size_t)m * K + (kt + 32) + kc * 8;
                gl_lds16(Ab + go, &As[nxt][ch * 8]);
                gl_lds16(Bb + go, &Bs[nxt][ch * 8]);
            }
        }
        bf16x8 af[4], bfr[4];
#pragma unroll
        for (int t = 0; t < 4; t++) {
            af[t]  = *(const bf16x8*)&As[cur][(wm + t * 16 + l16) * 32 + quad * 8];
            bfr[t] = *(const bf16x8*)&Bs[cur][(wn + t * 16 + l16) * 32 + quad * 8];
        }
#pragma unroll
        for (int mt = 0; mt < 4; mt++)
#pragma unroll
            for (int nt = 0; nt < 4; nt++)
                acc[mt][nt] = __builtin_amdgcn_mfma_f32_16x16x32_bf16(af[mt], bfr[nt], acc[mt][nt], 0, 0, 0);
        cur ^= 1;
    }

    // ---- write output ----
#pragma unroll
    for (int mt = 0; mt < 4; mt++) {
#pragma unroll
        for (int nt = 0; nt < 4; nt++) {
            int n = n0 + wn + nt * 16 + l16;
            float bv = bias[n];
            int mbase = m0 + wm + mt * 16 + quad * 4;
            if (!TRANS_OUT) {
                unsigned short* Y = (unsigned short*)Cout;
#pragma unroll
                for (int r = 0; r < 4; r++)
                    Y[(size_t)(mbase + r) * N + n] = f2b(acc[mt][nt][r] + bv);
            } else {
                float* Z = (float*)Cout;
                int b = mbase >> 10;
                int s = mbase & 1023;
                float4 v = make_float4(acc[mt][nt][0] + bv, acc[mt][nt][1] + bv,
                                       acc[mt][nt][2] + bv, acc[mt][nt][3] + bv);
                *(float4*)(&Z[((size_t)(b * 512 + n)) * 1024 + s]) = v;
            }
        }
    }

    // ---- fused a-sum accumulators ----
    // m_local = wm + mt*16 + quad*4 + r; h = m_local&31; w = wlo + (m_local>>5)
    if (DO_SUMS) {
        int b = m0 >> 10;
        int wlo = (m0 & 1023) >> 5; // first of 4 w-rows in this block
#pragma unroll
        for (int nt = 0; nt < 4; nt++) {
            int n = n0 + wn + nt * 16 + l16;
            float bv = bias[n];
            // total over this wave's 64 m's
            float tT = 0.f;
#pragma unroll
            for (int mt = 0; mt < 4; mt++)
#pragma unroll
                for (int r = 0; r < 4; r++) tT += acc[mt][nt][r] + bv;
            tT += __shfl_xor(tT, 16);
            tT += __shfl_xor(tT, 32);
            if (quad == 0) {
                atomicAdd(&Tsum[b * 1536 + n], tT);
                // h==0 rows: m_local = wm+{0,32} -> (mt 0,2, quad0, r0)
                float th0 = acc[0][nt][0] + acc[2][nt][0] + 2.f * bv;
                atomicAdd(&H0[b * 1536 + n], th0);
            }
            if (quad == 3) {
                // h==31 rows: m_local = wm+{31,63} -> (mt 1,3, quad3, r3)
                float th31 = acc[1][nt][3] + acc[3][nt][3] + 2.f * bv;
                atomicAdd(&H31[b * 1536 + n], th31);
            }
            if (wlo == 0 && wm == 0) { // w==0 slice: m_local < 32 -> mt 0,1
                float tc = 0.f;
#pragma unroll
                for (int mt = 0; mt < 2; mt++)
#pragma unroll
                    for (int r = 0; r < 4; r++) tc += acc[mt][nt][r] + bv;
                tc += __shfl_xor(tc, 16);
                tc += __shfl_xor(tc, 32);
                if (quad == 0) atomicAdd(&C0[b * 1536 + n], tc);
            }
            if (wlo == 28 && wm == 64) { // w==31 slice: m_local >= 96 -> mt 2,3
                float tc = 0.f;
#pragma unroll
                for (int mt = 2; mt < 4; mt++)
#pragma unroll
                    for (int r = 0; r < 4; r++) tc += acc[mt][nt][r] + bv;
                tc += __shfl_xor(tc, 16);
                tc += __shfl_xor(tc, 32);
                if (quad == 0) atomicAdd(&C31[b * 1536 + n], tc);
            }
        }
    }
}

// ---------- layer1: reconstruct a[b,:] from sum planes, then wave-dot ----------
// a[b,c]: q=c>>7, sgn=(q&1)?-1:+1,
//   e = (q<2) ? (C0-C31)[n1]+(H0-H31)[n2] : (H0-H31)[n1]+(C0-C31)[n2]
//   a = T[n1]+T[n2]+T[n3] + sgn*e       (n1=c, n2=512+c, n3=1024+c)
__global__ __launch_bounds__(256) void mlp_layer1(
    const float* __restrict__ sums, const float* __restrict__ wa,
    const float* __restrict__ ba, float* __restrict__ h)
{
    __shared__ float sa[512];
    int b = blockIdx.x >> 7;
    int t = threadIdx.x;
    const float* Tp   = sums;
    const float* H0p  = sums + 24576;
    const float* H31p = sums + 49152;
    const float* C0p  = sums + 73728;
    const float* C31p = sums + 98304;
#pragma unroll
    for (int j = 0; j < 2; j++) {
        int c = t + j * 256;
        int q = c >> 7;
        int n1 = b * 1536 + c;
        float t123 = Tp[n1] + Tp[n1 + 512] + Tp[n1 + 1024];
        float sC1 = C0p[n1] - C31p[n1];
        float sH1 = H0p[n1] - H31p[n1];
        float sC2 = C0p[n1 + 512] - C31p[n1 + 512];
        float sH2 = H0p[n1 + 512] - H31p[n1 + 512];
        float e = (q < 2) ? (sC1 + sH2) : (sH1 + sC2);
        sa[c] = t123 + ((q & 1) ? -e : e);
    }
    __syncthreads();
    int lane = t & 63, wid = t >> 6;
    int o = (blockIdx.x & 127) * 4 + wid;
    const float4* wr = (const float4*)(wa + (size_t)o * 512);
    float4 w0 = wr[lane * 2], w1v = wr[lane * 2 + 1];
    float4 a0 = ((const float4*)sa)[lane * 2], a1 = ((const float4*)sa)[lane * 2 + 1];
    float dot = w0.x * a0.x + w0.y * a0.y + w0.z * a0.z + w0.w * a0.w
              + w1v.x * a1.x + w1v.y * a1.y + w1v.z * a1.z + w1v.w * a1.w;
#pragma unroll
    for (int off = 32; off; off >>= 1) dot += __shfl_down(dot, off);
    if (lane == 0) {
        float v = dot + ba[o];
        h[b * 512 + o] = 0.5f * v * (1.0f + erff(v * 0.7071067811865475f));
    }
}

// ---------- layer2: hat[b*1536+o] = dot(h[b,:], wb[o,:]) + bb[o] ----------
__global__ __launch_bounds__(256) void mlp_layer2(
    const float* __restrict__ h, const float* __restrict__ wb,
    const float* __restrict__ bb, float* __restrict__ hat)
{
    int gw = (blockIdx.x * 256 + threadIdx.x) >> 6; // 24576 waves
    int lane = threadIdx.x & 63;
    int b = gw / 1536;
    int o = gw - b * 1536;
    const float4* wr = (const float4*)(wb + (size_t)o * 512);
    const float4* hr = (const float4*)(h + (size_t)b * 512);
    float4 w0 = wr[lane * 2], w1 = wr[lane * 2 + 1];
    float4 h0 = hr[lane * 2], h1 = hr[lane * 2 + 1];
    float dot = w0.x * h0.x + w0.y * h0.y + w0.z * h0.z + w0.w * h0.w
              + w1.x * h1.x + w1.y * h1.y + w1.z * h1.z + w1.w * h1.w;
#pragma unroll
    for (int off = 32; off; off >>= 1) dot += __shfl_down(dot, off);
    if (lane == 0)
        hat[(size_t)b * 1536 + o] = dot + bb[o];
}

// ---------- combine (softmax inline): out[b,s,c] = sum_j g_j * x_j (bf16) ----------
__global__ __launch_bounds__(256) void combine_softmax(
    const unsigned short* __restrict__ y, const float* __restrict__ hat,
    unsigned short* __restrict__ outT)
{
    int b = blockIdx.y;
    int t = threadIdx.x;
    int w = blockIdx.x * 4 + (t >> 6);
    int c8 = (t & 63) * 8;
    int q = c8 >> 7;
    int dw1 = (q == 0) ? -1 : (q == 1) ? 1 : 0;
    int dh1 = (q == 2) ? -1 : (q == 3) ? 1 : 0;
    int dh2 = (q == 0) ? -1 : (q == 1) ? 1 : 0;
    int dw2 = (q == 2) ? -1 : (q == 3) ? 1 : 0;
    float g0[8], g1[8], g2[8];
#pragma unroll
    for (int j = 0; j < 8; j++) {
        int c = c8 + j;
        float h0 = hat[b * 1536 + c];
        float h1 = hat[b * 1536 + 512 + c];
        float h2 = hat[b * 1536 + 1024 + c];
        float mx = fmaxf(h0, fmaxf(h1, h2));
        float e0 = __expf(h0 - mx), e1 = __expf(h1 - mx), e2 = __expf(h2 - mx);
        float inv = 1.0f / (e0 + e1 + e2);
        g0[j] = e0 * inv; g1[j] = e1 * inv; g2[j] = e2 * inv;
    }
    int w1i = min(max(w + dw1, 0), 31);
    int w2i = min(max(w + dw2, 0), 31);
    size_t base = (size_t)b * S_;
    for (int h = 0; h < 32; h++) {
        int h1i = min(max(h + dh1, 0), 31);
        int h2i = min(max(h + dh2, 0), 31);
        uint4 u1 = *(const uint4*)&y[(base + w1i * 32 + h1i) * N1 + c8];
        uint4 u2 = *(const uint4*)&y[(base + w2i * 32 + h2i) * N1 + 512 + c8];
        uint4 u3 = *(const uint4*)&y[(base + w * 32 + h) * N1 + 1024 + c8];
        unsigned int p[4];
        const unsigned int* a1 = &u1.x;
        const unsigned int* a2 = &u2.x;
        const unsigned int* a3 = &u3.x;
#pragma unroll
        for (int k = 0; k < 4; k++) {
            int j = k * 2;
            float lo = g0[j] * b2f(a1[k]) + g1[j] * b2f(a2[k]) + g2[j] * b2f(a3[k]);
            float hi = g0[j + 1] * b2f(a1[k] >> 16) + g1[j + 1] * b2f(a2[k] >> 16) + g2[j + 1] * b2f(a3[k] >> 16);
            p[k] = (unsigned int)f2b(lo) | ((unsigned int)f2b(hi) << 16);
        }
        *(uint4*)&outT[(base + w * 32 + h) * 512 + c8] = make_uint4(p[0], p[1], p[2], p[3]);
    }
}

extern "C" void kernel_launch(void* const* d_in, const int* in_sizes, int n_in,
                              void* d_out, int out_size, void* d_ws, size_t ws_size,
                              hipStream_t stream) {
    const float* x  = (const float*)d_in[0];
    const float* w1 = (const float*)d_in[1];
    const float* b1 = (const float*)d_in[2];
    const float* wa = (const float*)d_in[3];
    const float* ba = (const float*)d_in[4];
    const float* wb = (const float*)d_in[5];
    const float* bb = (const float*)d_in[6];
    const float* w2 = (const float*)d_in[7];
    const float* b2 = (const float*)d_in[8];
    float* out = (float*)d_out;

    char* ws = (char*)d_ws;
    unsigned short* xT   = (unsigned short*)(ws);              // 16 MB (dead after gemm1)
    unsigned short* outT = (unsigned short*)(ws);              // aliases xT (combine runs after gemm1)
    unsigned short* w1b  = (unsigned short*)(ws + 16777216);   // 1.5 MB
    unsigned short* w2b  = (unsigned short*)(ws + 18350080);   // 0.5 MB
    unsigned short* y    = (unsigned short*)(ws + 18874368);   // 48 MB: (B,S,3C) bf16
    float* sums          = (float*)(ws + 69206016);            // 5 x 96 KB: T,H0,H31,C0,C31
    float* h_buf         = (float*)(ws + 69697536);            // 32 KB
    float* hat_buf       = (float*)(ws + 69730304);            // 96 KB

    float* Tsum = sums;
    float* H0   = sums + 24576;
    float* H31  = sums + 49152;
    float* C0   = sums + 73728;
    float* C31  = sums + 98304;

    transpose_convert_x<<<dim3(32, 16, 16), dim3(32, 8), 0, stream>>>(x, xT);
    misc_prep<<<dim3(1144), dim3(256), 0, stream>>>(w1, w2, w1b, w2b, sums);
    gemm_bf16<false, true><<<dim3(128, 12), dim3(256), 0, stream>>>(
        xT, w1b, b1, (void*)y, 1536, Tsum, H0, H31, C0, C31);
    mlp_layer1<<<dim3(2048), dim3(256), 0, stream>>>(sums, wa, ba, h_buf);
    mlp_layer2<<<dim3(6144), dim3(256), 0, stream>>>(h_buf, wb, bb, hat_buf);
    combine_softmax<<<dim3(8, 16), dim3(256), 0, stream>>>(y, hat_buf, outT);
    gemm_bf16<true, false><<<dim3(128, 4), dim3(256), 0, stream>>>(
        outT, w2b, b2, (void*)out, 512, nullptr, nullptr, nullptr, nullptr, nullptr);
}